// Round 12
// baseline (278.172 us; speedup 1.0000x reference)
//
#include <hip/hip_runtime.h>
#include <math.h>

#define HW 65536
#define DD 160
#define NB 2
#define DCH 40
#define NSL (DCH + 6)   // 46 marched slices per chunk incl. halo
#define NCH 4
#define TW 32
#define TH 16
#define PH 23           // h-pitch (odd -> 2-way LDS access, free)

#define SSIM_C1 1e-4f
#define SSIM_C2 9e-4f

typedef float f32x2 __attribute__((ext_vector_type(2)));

struct Gw { float g[7]; };

static __device__ __forceinline__ f32x2 s2(float v) { f32x2 r; r.x = v; r.y = v; return r; }

// Fused SSIM3D v12: EXACT v7 (best known: 167us kernel — packed-fp32 fields,
// scalar direct loads, double-buffered transposed planes, DCH=40, 1024 blocks)
// with ONE change: the per-slice __syncthreads() is replaced by
// s_waitcnt lgkmcnt(0) + s_barrier. The vmcnt drain that __syncthreads implies
// is semantically unnecessary (prefetch loads land in private VGPRs); removing
// it lets the 20 prefetch loads stay in flight across the barrier (T3/T4).
__global__ __launch_bounds__(256, 2) void k_fused(
    const float* __restrict__ img1, const float* __restrict__ img2,
    Gw gw, float* __restrict__ partials)
{
    __shared__ f32x2 pA[2][TW][PH];   // (conv_w x, conv_w y)
    __shared__ f32x2 pB[2][TW][PH];   // (conv_w xx, conv_w yy)
    __shared__ float pC[2][TW][PH];   // conv_w xy
    __shared__ float red[256];

    const int tid = threadIdx.x;
    const int nb = blockIdx.z >> 2;
    const int o0 = (blockIdx.z & 3) * DCH;
    const int h0 = blockIdx.y * TH;
    const int w0 = blockIdx.x * TW;
    const float* i1 = img1 + (size_t)nb * DD * HW;
    const float* i2 = img2 + (size_t)nb * DD * HW;

    // ---- W-thread geometry (tid < 176): row hh (0..21), 4 outputs at wb ----
    const bool wth = (tid < 176);
    const int hh = tid >> 3;
    const int wb = (tid & 7) * 4;
    const int gh = h0 - 3 + hh;
    const int gwb = w0 - 3 + wb;
    const bool ghv = wth && ((unsigned)gh < 256u);
    const int ghc = gh < 0 ? 0 : (gh > 255 ? 255 : gh);
    int coff[10];
    unsigned wbits = 0;
#pragma unroll
    for (int i = 0; i < 10; ++i) {
        int gwi = gwb + i;
        int gc = gwi < 0 ? 0 : (gwi > 255 ? 255 : gwi);
        coff[i] = ghc * 256 + gc;                 // always-in-bounds address
        if (ghv && gwi == gc) wbits |= (1u << i); // zero-pad mask bit
    }

    // ---- H/D geometry: all 256 threads, 2 output rows each ----
    const int wcol = tid & 31;
    const int hb = (tid >> 5) * 2;   // 0..14

    f32x2 ringA[2][7] = {};
    f32x2 ringB[2][7] = {};
    float ringC[2][7] = {};
    float lsum = 0.f;
    f32x2 cxy[10];

    // slice loader (v7-identical): scalar loads direct to final regs, masked
    auto LOAD = [&](int s) {
        const float* p1 = i1 + (size_t)s * HW;
        const float* p2 = i2 + (size_t)s * HW;
#pragma unroll
        for (int i = 0; i < 10; ++i) {
            const float vx = p1[coff[i]];
            const float vy = p2[coff[i]];
            const bool ok = (wbits >> i) & 1u;
            cxy[i].x = ok ? vx : 0.f;
            cxy[i].y = ok ? vy : 0.f;
        }
    };

    // prologue: load slice r=0 (s = o0-3)
    {
        const int s0 = o0 - 3;
        if (s0 >= 0 && wth) LOAD(s0);
    }

    for (int t = 0; t < 7; ++t) {
#pragma unroll
        for (int p = 0; p < 7; ++p) {
            const int r = 7 * t + p;
            if (r <= NSL) {
                const int scur = o0 - 3 + r;
                const bool wv = (r < NSL) && (scur >= 0) && (scur < DD);
                const int snx = scur + 1;
                const bool pfv = (r + 1 < NSL) && (snx >= 0) && (snx < DD);

                // 1) W-pass from registers -> planes[r&1]
                if (wv && wth) {
                    f32x2 aA[4] = {};
                    f32x2 aB[4] = {};
                    float aC[4] = {};
#pragma unroll
                    for (int i = 0; i < 10; ++i) {
                        const f32x2 xi2 = cxy[i];
                        const f32x2 xx2 = xi2 * xi2;      // v_pk_mul_f32
                        const float xy = xi2.x * xi2.y;
#pragma unroll
                        for (int o = 0; o < 4; ++o) {
                            const int k = i - o;
                            if (k >= 0 && k < 7) {
                                const float gk = gw.g[k];
                                aA[o] += s2(gk) * xi2;    // v_pk_fma_f32
                                aB[o] += s2(gk) * xx2;
                                aC[o] += gk * xy;
                            }
                        }
                    }
                    const int buf = r & 1;
#pragma unroll
                    for (int o = 0; o < 4; ++o) {
                        pA[buf][wb + o][hh] = aA[o];
                        pB[buf][wb + o][hh] = aB[o];
                        pC[buf][wb + o][hh] = aC[o];
                    }
                }

                // 2) prefetch next slice into cxy (consumed next iteration)
                if (pfv && wth) LOAD(snx);

                // 3) H-pass + D-ring + SSIM for slice rp = r-1 (other buffer)
                if (r >= 1) {
                    const int rp = r - 1;
                    const int sp = o0 - 3 + rp;
                    const int pi = (p + 6) % 7;   // == rp % 7, compile-time
                    if (sp >= 0 && sp < DD) {
                        const int buf = rp & 1;
                        f32x2 vA[8], vB[8];
                        float vC[8];
#pragma unroll
                        for (int i = 0; i < 8; ++i) {
                            vA[i] = pA[buf][wcol][hb + i];
                            vB[i] = pB[buf][wcol][hb + i];
                            vC[i] = pC[buf][wcol][hb + i];
                        }
#pragma unroll
                        for (int o = 0; o < 2; ++o) {
                            f32x2 aA = s2(0.f), aB = s2(0.f);
                            float aC = 0.f;
#pragma unroll
                            for (int k = 0; k < 7; ++k) {
                                const float gk = gw.g[k];
                                aA += s2(gk) * vA[o + k];
                                aB += s2(gk) * vB[o + k];
                                aC += gk * vC[o + k];
                            }
                            ringA[o][pi] = aA;
                            ringB[o][pi] = aB;
                            ringC[o][pi] = aC;
                        }
                    } else {
#pragma unroll
                        for (int o = 0; o < 2; ++o) {
                            ringA[o][pi] = s2(0.f);
                            ringB[o][pi] = s2(0.f);
                            ringC[o][pi] = 0.f;
                        }
                    }
                    if (r >= 7) {
                        f32x2 CA[2], CB[2];
                        float CC[2];
#pragma unroll
                        for (int o = 0; o < 2; ++o) {
                            f32x2 cA = s2(0.f), cB = s2(0.f);
                            float cC = 0.f;
#pragma unroll
                            for (int k = 0; k < 7; ++k) {
                                const float gk = gw.g[k];
                                const int pp = (pi + 1 + k) % 7;
                                cA += s2(gk) * ringA[o][pp];
                                cB += s2(gk) * ringB[o][pp];
                                cC += gk * ringC[o][pp];
                            }
                            CA[o] = cA; CB[o] = cB; CC[o] = cC;
                        }
                        // packed SSIM over the two h-outputs
                        f32x2 mu1, mu2, E11, E22, E12;
                        mu1.x = CA[0].x; mu1.y = CA[1].x;
                        mu2.x = CA[0].y; mu2.y = CA[1].y;
                        E11.x = CB[0].x; E11.y = CB[1].x;
                        E22.x = CB[0].y; E22.y = CB[1].y;
                        E12.x = CC[0];   E12.y = CC[1];
                        const f32x2 mu1s = mu1 * mu1;
                        const f32x2 mu2s = mu2 * mu2;
                        const f32x2 m12 = mu1 * mu2;
                        const f32x2 sg1 = E11 - mu1s;
                        const f32x2 sg2 = E22 - mu2s;
                        const f32x2 s12 = E12 - m12;
                        const f32x2 num = (s2(2.f) * m12 + s2(SSIM_C1)) *
                                          (s2(2.f) * s12 + s2(SSIM_C2));
                        const f32x2 den = (mu1s + mu2s + s2(SSIM_C1)) *
                                          (sg1 + sg2 + s2(SSIM_C2));
                        lsum += num.x * __builtin_amdgcn_rcpf(den.x)
                              + num.y * __builtin_amdgcn_rcpf(den.y);
                    }
                }

                // slice barrier: make ds_writes visible WITHOUT draining vmcnt —
                // prefetch loads (private VGPR destinations) stay in flight.
                asm volatile("s_waitcnt lgkmcnt(0)" ::: "memory");
                __builtin_amdgcn_s_barrier();
            }
        }
    }

    // deterministic block reduction (full __syncthreads is fine here)
    red[tid] = lsum;
    __syncthreads();
    for (int off = 128; off > 0; off >>= 1) {
        if (tid < off) red[tid] += red[tid + off];
        __syncthreads();
    }
    if (tid == 0)
        partials[(blockIdx.z * gridDim.y + blockIdx.y) * gridDim.x + blockIdx.x] = red[0];
}

__global__ __launch_bounds__(256) void k_final(
    const float* __restrict__ partials, int n, float scale, float* __restrict__ out)
{
    __shared__ float red[256];
    float s = 0.f;
    for (int i = threadIdx.x; i < n; i += 256) s += partials[i];
    red[threadIdx.x] = s;
    __syncthreads();
    for (int off = 128; off > 0; off >>= 1) {
        if (threadIdx.x < off) red[threadIdx.x] += red[threadIdx.x + off];
        __syncthreads();
    }
    if (threadIdx.x == 0) out[0] = red[0] * scale;
}

extern "C" void kernel_launch(void* const* d_in, const int* in_sizes, int n_in,
                              void* d_out, int out_size, void* d_ws, size_t ws_size,
                              hipStream_t stream)
{
    const float* img1 = (const float*)d_in[0];
    const float* img2 = (const float*)d_in[1];
    float* out = (float*)d_out;
    float* partials = (float*)d_ws;

    Gw gw;
    {
        double gs[7], sum = 0.0;
        for (int i = 0; i < 7; ++i) { double x = i - 3; gs[i] = exp(-x * x / 4.5); sum += gs[i]; }
        for (int i = 0; i < 7; ++i) gw.g[i] = (float)(gs[i] / sum);
    }

    dim3 grid(256 / TW, 256 / TH, NB * NCH);   // 8 x 16 x 8 = 1024 blocks
    k_fused<<<grid, dim3(256), 0, stream>>>(img1, img2, gw, partials);
    k_final<<<dim3(1), dim3(256), 0, stream>>>(
        partials, (256 / TW) * (256 / TH) * NB * NCH, (float)(1.0 / 20971520.0), out);
}

// Round 13
// 264.816 us; speedup vs baseline: 1.0504x; 1.0504x over previous
//
#include <hip/hip_runtime.h>
#include <math.h>

#define HW 65536
#define DD 160
#define NB 2
#define DCH 40
#define NSL (DCH + 6)   // 46 marched slices per chunk incl. halo
#define NCH 4
#define TW 32
#define TH 16
#define PH 23           // h-pitch (odd -> 2-way LDS access, free)

#define SSIM_C1 1e-4f
#define SSIM_C2 9e-4f

typedef float f32x2 __attribute__((ext_vector_type(2)));

struct Gw { float g[7]; };

static __device__ __forceinline__ f32x2 s2(float v) { f32x2 r; r.x = v; r.y = v; return r; }

// Fused SSIM3D v13: EXACT v7 structure (the 167us champion: scalar masked
// direct loads, double-buffered transposed f32x2 planes, one plain
// __syncthreads per slice, DCH=40, 1024 blocks) with ONE change: the u/v
// field algebra. u=x+y, v=x-y -> conv fields {u,v,u^2,v^2} in two f32x2
// planes (pC deleted). SSIM recovered from A,B,P,Q at the tail.
__global__ __launch_bounds__(256, 2) void k_fused(
    const float* __restrict__ img1, const float* __restrict__ img2,
    Gw gw, float* __restrict__ partials)
{
    __shared__ f32x2 pUV[2][TW][PH];   // (conv_w u, conv_w v)
    __shared__ f32x2 pSQ[2][TW][PH];   // (conv_w u^2, conv_w v^2)
    __shared__ float red[256];

    const int tid = threadIdx.x;
    const int nb = blockIdx.z >> 2;
    const int o0 = (blockIdx.z & 3) * DCH;
    const int h0 = blockIdx.y * TH;
    const int w0 = blockIdx.x * TW;
    const float* i1 = img1 + (size_t)nb * DD * HW;
    const float* i2 = img2 + (size_t)nb * DD * HW;

    // ---- W-thread geometry (tid < 176): row hh (0..21), 4 outputs at wb ----
    const bool wth = (tid < 176);
    const int hh = tid >> 3;
    const int wb = (tid & 7) * 4;
    const int gh = h0 - 3 + hh;
    const int gwb = w0 - 3 + wb;
    const bool ghv = wth && ((unsigned)gh < 256u);
    const int ghc = gh < 0 ? 0 : (gh > 255 ? 255 : gh);
    int coff[10];
    unsigned wbits = 0;
#pragma unroll
    for (int i = 0; i < 10; ++i) {
        int gwi = gwb + i;
        int gc = gwi < 0 ? 0 : (gwi > 255 ? 255 : gwi);
        coff[i] = ghc * 256 + gc;                 // always-in-bounds address
        if (ghv && gwi == gc) wbits |= (1u << i); // zero-pad mask bit
    }

    // ---- H/D geometry: all 256 threads, 2 output rows each ----
    const int wcol = tid & 31;
    const int hb = (tid >> 5) * 2;   // 0..14

    f32x2 ringUV[2][7] = {};
    f32x2 ringSQ[2][7] = {};
    float lsum = 0.f;
    f32x2 cxy[10];   // raw (x,y); transform happens at W-pass consumption

    // slice loader (v7-identical): scalar loads direct to final regs, masked
    auto LOAD = [&](int s) {
        const float* p1 = i1 + (size_t)s * HW;
        const float* p2 = i2 + (size_t)s * HW;
#pragma unroll
        for (int i = 0; i < 10; ++i) {
            const float vx = p1[coff[i]];
            const float vy = p2[coff[i]];
            const bool ok = (wbits >> i) & 1u;
            cxy[i].x = ok ? vx : 0.f;
            cxy[i].y = ok ? vy : 0.f;
        }
    };

    // prologue: load slice r=0 (s = o0-3)
    {
        const int s0 = o0 - 3;
        if (s0 >= 0 && wth) LOAD(s0);
    }

    for (int t = 0; t < 7; ++t) {
#pragma unroll
        for (int p = 0; p < 7; ++p) {
            const int r = 7 * t + p;
            if (r <= NSL) {
                const int scur = o0 - 3 + r;
                const bool wv = (r < NSL) && (scur >= 0) && (scur < DD);
                const int snx = scur + 1;
                const bool pfv = (r + 1 < NSL) && (snx >= 0) && (snx < DD);

                // 1) W-pass from registers -> planes[r&1] (u/v transform here,
                //    one full phase after the loads were issued)
                if (wv && wth) {
                    f32x2 aUV[4] = {};
                    f32x2 aSQ[4] = {};
#pragma unroll
                    for (int i = 0; i < 10; ++i) {
                        f32x2 uv;
                        uv.x = cxy[i].x + cxy[i].y;
                        uv.y = cxy[i].x - cxy[i].y;
                        const f32x2 sq = uv * uv;         // v_pk_mul_f32
#pragma unroll
                        for (int o = 0; o < 4; ++o) {
                            const int k = i - o;
                            if (k >= 0 && k < 7) {
                                const float gk = gw.g[k];
                                aUV[o] += s2(gk) * uv;    // v_pk_fma_f32
                                aSQ[o] += s2(gk) * sq;
                            }
                        }
                    }
                    const int buf = r & 1;
#pragma unroll
                    for (int o = 0; o < 4; ++o) {
                        pUV[buf][wb + o][hh] = aUV[o];
                        pSQ[buf][wb + o][hh] = aSQ[o];
                    }
                }

                // 2) prefetch next slice into cxy (consumed next iteration)
                if (pfv && wth) LOAD(snx);

                // 3) H-pass + D-ring + SSIM for slice rp = r-1 (other buffer)
                if (r >= 1) {
                    const int rp = r - 1;
                    const int sp = o0 - 3 + rp;
                    const int pi = (p + 6) % 7;   // == rp % 7, compile-time
                    if (sp >= 0 && sp < DD) {
                        const int buf = rp & 1;
                        f32x2 vU[8], vS[8];
#pragma unroll
                        for (int i = 0; i < 8; ++i) {
                            vU[i] = pUV[buf][wcol][hb + i];
                            vS[i] = pSQ[buf][wcol][hb + i];
                        }
#pragma unroll
                        for (int o = 0; o < 2; ++o) {
                            f32x2 aU = s2(0.f), aS = s2(0.f);
#pragma unroll
                            for (int k = 0; k < 7; ++k) {
                                const float gk = gw.g[k];
                                aU += s2(gk) * vU[o + k];
                                aS += s2(gk) * vS[o + k];
                            }
                            ringUV[o][pi] = aU;
                            ringSQ[o][pi] = aS;
                        }
                    } else {
#pragma unroll
                        for (int o = 0; o < 2; ++o) {
                            ringUV[o][pi] = s2(0.f);
                            ringSQ[o][pi] = s2(0.f);
                        }
                    }
                    if (r >= 7) {
#pragma unroll
                        for (int o = 0; o < 2; ++o) {
                            f32x2 cU = s2(0.f), cS = s2(0.f);
#pragma unroll
                            for (int k = 0; k < 7; ++k) {
                                const float gk = gw.g[k];
                                const int pp = (pi + 1 + k) % 7;
                                cU += s2(gk) * ringUV[o][pp];
                                cS += s2(gk) * ringSQ[o][pp];
                            }
                            // A=conv(u), B=conv(v), P=conv(u^2), Q=conv(v^2)
                            const f32x2 ab2 = cU * cU;          // (A^2, B^2)
                            const float sAB = ab2.x + ab2.y;
                            const float dAB = ab2.x - ab2.y;
                            const float sPQ = cS.x + cS.y;
                            const float dPQ = cS.x - cS.y;
                            const float num1 = 0.5f * dAB + SSIM_C1;          // 2mu1mu2+C1
                            const float num2 = 0.5f * (dPQ - dAB) + SSIM_C2;  // 2sig12+C2
                            const float den1 = 0.5f * sAB + SSIM_C1;          // mu1^2+mu2^2+C1
                            const float den2 = 0.5f * (sPQ - sAB) + SSIM_C2;  // sig1+sig2+C2
                            lsum += (num1 * num2) * __builtin_amdgcn_rcpf(den1 * den2);
                        }
                    }
                }
                __syncthreads();
            }
        }
    }

    // deterministic block reduction
    red[tid] = lsum;
    __syncthreads();
    for (int off = 128; off > 0; off >>= 1) {
        if (tid < off) red[tid] += red[tid + off];
        __syncthreads();
    }
    if (tid == 0)
        partials[(blockIdx.z * gridDim.y + blockIdx.y) * gridDim.x + blockIdx.x] = red[0];
}

__global__ __launch_bounds__(256) void k_final(
    const float* __restrict__ partials, int n, float scale, float* __restrict__ out)
{
    __shared__ float red[256];
    float s = 0.f;
    for (int i = threadIdx.x; i < n; i += 256) s += partials[i];
    red[threadIdx.x] = s;
    __syncthreads();
    for (int off = 128; off > 0; off >>= 1) {
        if (threadIdx.x < off) red[threadIdx.x] += red[threadIdx.x + off];
        __syncthreads();
    }
    if (threadIdx.x == 0) out[0] = red[0] * scale;
}

extern "C" void kernel_launch(void* const* d_in, const int* in_sizes, int n_in,
                              void* d_out, int out_size, void* d_ws, size_t ws_size,
                              hipStream_t stream)
{
    const float* img1 = (const float*)d_in[0];
    const float* img2 = (const float*)d_in[1];
    float* out = (float*)d_out;
    float* partials = (float*)d_ws;

    Gw gw;
    {
        double gs[7], sum = 0.0;
        for (int i = 0; i < 7; ++i) { double x = i - 3; gs[i] = exp(-x * x / 4.5); sum += gs[i]; }
        for (int i = 0; i < 7; ++i) gw.g[i] = (float)(gs[i] / sum);
    }

    dim3 grid(256 / TW, 256 / TH, NB * NCH);   // 8 x 16 x 8 = 1024 blocks
    k_fused<<<grid, dim3(256), 0, stream>>>(img1, img2, gw, partials);
    k_final<<<dim3(1), dim3(256), 0, stream>>>(
        partials, (256 / TW) * (256 / TH) * NB * NCH, (float)(1.0 / 20971520.0), out);
}

// Round 14
// 153.130 us; speedup vs baseline: 1.8166x; 1.7294x over previous
//
#include <hip/hip_runtime.h>
#include <math.h>

#define HW 65536
#define DD 160
#define NB 2
#define DCH 40
#define NSL (DCH + 6)   // 46 marched slices per chunk incl. halo
#define NCH 4
#define TW 32
#define TH 16
#define PH 23           // h-pitch (odd -> 2-way LDS access, free)

#define SSIM_C1 1e-4f
#define SSIM_C2 9e-4f

typedef float f32x2 __attribute__((ext_vector_type(2)));

struct Gw { float g[7]; };

static __device__ __forceinline__ f32x2 s2(float v) { f32x2 r; r.x = v; r.y = v; return r; }

// Fused SSIM3D v14: EXACT v7 algebra/structure (5 packed fields, double-buffered
// transposed planes, plain __syncthreads per slice, DCH=40, 1024 blocks) with
// DEPTH-2 ping-pong register prefetch: iteration r consumes buf[r&1] (loaded at
// r-2), then refills it with slice r+2. ~2 iterations of in-flight slack makes
// latency hiding structural instead of schedule-luck. LOADTO is 20 raw loads
// (no dependent VALU at issue site); zero-pad masking done at consumption via
// precomputed multipliers. 14-phase unroll makes buffer parity compile-time.
__global__ __launch_bounds__(256, 2) void k_fused(
    const float* __restrict__ img1, const float* __restrict__ img2,
    Gw gw, float* __restrict__ partials)
{
    __shared__ f32x2 pA[2][TW][PH];   // (conv_w x, conv_w y)
    __shared__ f32x2 pB[2][TW][PH];   // (conv_w xx, conv_w yy)
    __shared__ float pC[2][TW][PH];   // conv_w xy
    __shared__ float red[256];

    const int tid = threadIdx.x;
    const int nb = blockIdx.z >> 2;
    const int o0 = (blockIdx.z & 3) * DCH;
    const int h0 = blockIdx.y * TH;
    const int w0 = blockIdx.x * TW;
    const float* i1 = img1 + (size_t)nb * DD * HW;
    const float* i2 = img2 + (size_t)nb * DD * HW;

    // ---- W-thread geometry (tid < 176): row hh (0..21), 4 outputs at wb ----
    const bool wth = (tid < 176);
    const int hh = tid >> 3;
    const int wb = (tid & 7) * 4;
    const int gh = h0 - 3 + hh;
    const int gwb = w0 - 3 + wb;
    const bool ghv = wth && ((unsigned)gh < 256u);
    const int ghc = gh < 0 ? 0 : (gh > 255 ? 255 : gh);
    int coff[10];
    float mx[10];
#pragma unroll
    for (int i = 0; i < 10; ++i) {
        int gwi = gwb + i;
        int gc = gwi < 0 ? 0 : (gwi > 255 ? 255 : gwi);
        coff[i] = ghc * 256 + gc;                      // always-in-bounds address
        mx[i] = (ghv && gwi == gc) ? 1.f : 0.f;        // zero-pad multiplier
    }

    // ---- H/D geometry: all 256 threads, 2 output rows each ----
    const int wcol = tid & 31;
    const int hb = (tid >> 5) * 2;   // 0..14

    f32x2 ringA[2][7] = {};
    f32x2 ringB[2][7] = {};
    float ringC[2][7] = {};
    float lsum = 0.f;
    f32x2 cA[10], cB[10];   // depth-2 ping-pong slice buffers (raw x,y)

    // raw slice loader: 20 independent loads, NO dependent VALU at issue site
    auto LOADTO = [&](f32x2 (&buf)[10], int s) {
        const float* p1 = i1 + (size_t)s * HW;
        const float* p2 = i2 + (size_t)s * HW;
#pragma unroll
        for (int i = 0; i < 10; ++i) buf[i].x = p1[coff[i]];
#pragma unroll
        for (int i = 0; i < 10; ++i) buf[i].y = p2[coff[i]];
    };

    // prologue: slice r=0 -> cA, slice r=1 -> cB (skipped if out of range;
    // W-pass is also skipped for those r, so buffer contents don't matter)
    {
        const int s0 = o0 - 3;
        if (s0 >= 0 && wth) LOADTO(cA, s0);
        const int s1 = o0 - 2;
        if (s1 >= 0 && wth) LOADTO(cB, s1);
    }

#define PHASE(Q, CUR)                                                         \
    {                                                                         \
        const int r = 14 * t2 + (Q);                                          \
        if (r <= NSL) {                                                       \
            const int scur = o0 - 3 + r;                                      \
            const bool wv = (r < NSL) && (scur >= 0) && (scur < DD);          \
            /* 1) W-pass consumes CUR (loaded 2 iterations ago) */            \
            if (wv && wth) {                                                  \
                f32x2 aA[4] = {};                                             \
                f32x2 aB[4] = {};                                             \
                float aC[4] = {};                                             \
                _Pragma("unroll")                                             \
                for (int i = 0; i < 10; ++i) {                                \
                    const f32x2 xi2 = CUR[i] * s2(mx[i]);                     \
                    const f32x2 xx2 = xi2 * xi2;                              \
                    const float xy = xi2.x * xi2.y;                           \
                    _Pragma("unroll")                                         \
                    for (int o = 0; o < 4; ++o) {                             \
                        const int k = i - o;                                  \
                        if (k >= 0 && k < 7) {                                \
                            const float gk = gw.g[k];                         \
                            aA[o] += s2(gk) * xi2;                            \
                            aB[o] += s2(gk) * xx2;                            \
                            aC[o] += gk * xy;                                 \
                        }                                                     \
                    }                                                         \
                }                                                             \
                _Pragma("unroll")                                             \
                for (int o = 0; o < 4; ++o) {                                 \
                    pA[(Q) & 1][wb + o][hh] = aA[o];                          \
                    pB[(Q) & 1][wb + o][hh] = aB[o];                          \
                    pC[(Q) & 1][wb + o][hh] = aC[o];                          \
                }                                                             \
            }                                                                 \
            /* 2) depth-2 prefetch: slice r+2 into CUR (consumed at r+2) */   \
            {                                                                 \
                const int sn2 = scur + 2;                                     \
                if ((r + 2 < NSL) && (sn2 >= 0) && (sn2 < DD) && wth)         \
                    LOADTO(CUR, sn2);                                         \
            }                                                                 \
            /* 3) H-pass + D-ring + SSIM for rp = r-1 (other plane buffer) */ \
            if (r >= 1) {                                                     \
                const int rp = r - 1;                                         \
                const int sp = o0 - 3 + rp;                                   \
                if (sp >= 0 && sp < DD) {                                     \
                    f32x2 vA[8], vB[8];                                       \
                    float vC[8];                                              \
                    _Pragma("unroll")                                         \
                    for (int i = 0; i < 8; ++i) {                             \
                        vA[i] = pA[((Q) + 1) & 1][wcol][hb + i];              \
                        vB[i] = pB[((Q) + 1) & 1][wcol][hb + i];              \
                        vC[i] = pC[((Q) + 1) & 1][wcol][hb + i];              \
                    }                                                         \
                    _Pragma("unroll")                                         \
                    for (int o = 0; o < 2; ++o) {                             \
                        f32x2 aA = s2(0.f), aB = s2(0.f);                     \
                        float aC = 0.f;                                       \
                        _Pragma("unroll")                                     \
                        for (int k = 0; k < 7; ++k) {                         \
                            const float gk = gw.g[k];                         \
                            aA += s2(gk) * vA[o + k];                         \
                            aB += s2(gk) * vB[o + k];                         \
                            aC += gk * vC[o + k];                             \
                        }                                                     \
                        ringA[o][((Q) + 6) % 7] = aA;                         \
                        ringB[o][((Q) + 6) % 7] = aB;                         \
                        ringC[o][((Q) + 6) % 7] = aC;                         \
                    }                                                         \
                } else {                                                      \
                    _Pragma("unroll")                                         \
                    for (int o = 0; o < 2; ++o) {                             \
                        ringA[o][((Q) + 6) % 7] = s2(0.f);                    \
                        ringB[o][((Q) + 6) % 7] = s2(0.f);                    \
                        ringC[o][((Q) + 6) % 7] = 0.f;                        \
                    }                                                         \
                }                                                             \
                if (r >= 7) {                                                 \
                    f32x2 CAq[2], CBq[2];                                     \
                    float CCq[2];                                             \
                    _Pragma("unroll")                                         \
                    for (int o = 0; o < 2; ++o) {                             \
                        f32x2 cAa = s2(0.f), cBa = s2(0.f);                   \
                        float cCa = 0.f;                                      \
                        _Pragma("unroll")                                     \
                        for (int k = 0; k < 7; ++k) {                         \
                            const float gk = gw.g[k];                         \
                            const int pp = (((Q) + 6) % 7 + 1 + k) % 7;       \
                            cAa += s2(gk) * ringA[o][pp];                     \
                            cBa += s2(gk) * ringB[o][pp];                     \
                            cCa += gk * ringC[o][pp];                         \
                        }                                                     \
                        CAq[o] = cAa; CBq[o] = cBa; CCq[o] = cCa;             \
                    }                                                         \
                    f32x2 mu1, mu2, E11, E22, E12;                            \
                    mu1.x = CAq[0].x; mu1.y = CAq[1].x;                       \
                    mu2.x = CAq[0].y; mu2.y = CAq[1].y;                       \
                    E11.x = CBq[0].x; E11.y = CBq[1].x;                       \
                    E22.x = CBq[0].y; E22.y = CBq[1].y;                       \
                    E12.x = CCq[0];   E12.y = CCq[1];                         \
                    const f32x2 mu1s = mu1 * mu1;                             \
                    const f32x2 mu2s = mu2 * mu2;                             \
                    const f32x2 m12 = mu1 * mu2;                              \
                    const f32x2 sg1 = E11 - mu1s;                             \
                    const f32x2 sg2 = E22 - mu2s;                             \
                    const f32x2 s12 = E12 - m12;                              \
                    const f32x2 num = (s2(2.f) * m12 + s2(SSIM_C1)) *         \
                                      (s2(2.f) * s12 + s2(SSIM_C2));          \
                    const f32x2 den = (mu1s + mu2s + s2(SSIM_C1)) *           \
                                      (sg1 + sg2 + s2(SSIM_C2));              \
                    lsum += num.x * __builtin_amdgcn_rcpf(den.x)              \
                          + num.y * __builtin_amdgcn_rcpf(den.y);             \
                }                                                             \
            }                                                                 \
            __syncthreads();                                                  \
        }                                                                     \
    }

    for (int t2 = 0; t2 < 4; ++t2) {
        PHASE(0, cA)  PHASE(1, cB)  PHASE(2, cA)  PHASE(3, cB)
        PHASE(4, cA)  PHASE(5, cB)  PHASE(6, cA)  PHASE(7, cB)
        PHASE(8, cA)  PHASE(9, cB)  PHASE(10, cA) PHASE(11, cB)
        PHASE(12, cA) PHASE(13, cB)
    }
#undef PHASE

    // deterministic block reduction
    red[tid] = lsum;
    __syncthreads();
    for (int off = 128; off > 0; off >>= 1) {
        if (tid < off) red[tid] += red[tid + off];
        __syncthreads();
    }
    if (tid == 0)
        partials[(blockIdx.z * gridDim.y + blockIdx.y) * gridDim.x + blockIdx.x] = red[0];
}

__global__ __launch_bounds__(256) void k_final(
    const float* __restrict__ partials, int n, float scale, float* __restrict__ out)
{
    __shared__ float red[256];
    float s = 0.f;
    for (int i = threadIdx.x; i < n; i += 256) s += partials[i];
    red[threadIdx.x] = s;
    __syncthreads();
    for (int off = 128; off > 0; off >>= 1) {
        if (threadIdx.x < off) red[threadIdx.x] += red[threadIdx.x + off];
        __syncthreads();
    }
    if (threadIdx.x == 0) out[0] = red[0] * scale;
}

extern "C" void kernel_launch(void* const* d_in, const int* in_sizes, int n_in,
                              void* d_out, int out_size, void* d_ws, size_t ws_size,
                              hipStream_t stream)
{
    const float* img1 = (const float*)d_in[0];
    const float* img2 = (const float*)d_in[1];
    float* out = (float*)d_out;
    float* partials = (float*)d_ws;

    Gw gw;
    {
        double gs[7], sum = 0.0;
        for (int i = 0; i < 7; ++i) { double x = i - 3; gs[i] = exp(-x * x / 4.5); sum += gs[i]; }
        for (int i = 0; i < 7; ++i) gw.g[i] = (float)(gs[i] / sum);
    }

    dim3 grid(256 / TW, 256 / TH, NB * NCH);   // 8 x 16 x 8 = 1024 blocks
    k_fused<<<grid, dim3(256), 0, stream>>>(img1, img2, gw, partials);
    k_final<<<dim3(1), dim3(256), 0, stream>>>(
        partials, (256 / TW) * (256 / TH) * NB * NCH, (float)(1.0 / 20971520.0), out);
}

// Round 15
// 152.023 us; speedup vs baseline: 1.8298x; 1.0073x over previous
//
#include <hip/hip_runtime.h>
#include <math.h>

#define HW 65536
#define DD 160
#define NB 2
#define DCH 40
#define NSL (DCH + 6)   // 46 marched slices per chunk incl. halo
#define NCH 4
#define TW 32
#define TH 16
#define PH 23           // h-pitch (odd -> 2-way LDS access, free)

#define SSIM_C1 1e-4f
#define SSIM_C2 9e-4f

typedef float f32x2 __attribute__((ext_vector_type(2)));

struct Gw { float g[7]; };

static __device__ __forceinline__ f32x2 s2(float v) { f32x2 r; r.x = v; r.y = v; return r; }

// Fused SSIM3D v15: R14's depth-2 ping-pong skeleton (structural latency
// hiding: slice r consumes buf[r&1] loaded at r-2, refills it with r+2;
// 14-phase compile-time unroll; raw-load issue sites; multiplier masking at
// consumption) combined with the u/v field algebra (u=x+y, v=x-y -> 4 conv
// fields {u,v,u^2,v^2} in two f32x2 planes; pC deleted). LDS 24.6KB -> 6
// blocks/CU by LDS. R13 proved the algebra's busy-cut; R14 proved depth-2
// caps the stall that killed R13.
__global__ __launch_bounds__(256, 2) void k_fused(
    const float* __restrict__ img1, const float* __restrict__ img2,
    Gw gw, float* __restrict__ partials)
{
    __shared__ f32x2 pUV[2][TW][PH];   // (conv_w u, conv_w v)
    __shared__ f32x2 pSQ[2][TW][PH];   // (conv_w u^2, conv_w v^2)
    __shared__ float red[256];

    const int tid = threadIdx.x;
    const int nb = blockIdx.z >> 2;
    const int o0 = (blockIdx.z & 3) * DCH;
    const int h0 = blockIdx.y * TH;
    const int w0 = blockIdx.x * TW;
    const float* i1 = img1 + (size_t)nb * DD * HW;
    const float* i2 = img2 + (size_t)nb * DD * HW;

    // ---- W-thread geometry (tid < 176): row hh (0..21), 4 outputs at wb ----
    const bool wth = (tid < 176);
    const int hh = tid >> 3;
    const int wb = (tid & 7) * 4;
    const int gh = h0 - 3 + hh;
    const int gwb = w0 - 3 + wb;
    const bool ghv = wth && ((unsigned)gh < 256u);
    const int ghc = gh < 0 ? 0 : (gh > 255 ? 255 : gh);
    int coff[10];
    float mx[10];
#pragma unroll
    for (int i = 0; i < 10; ++i) {
        int gwi = gwb + i;
        int gc = gwi < 0 ? 0 : (gwi > 255 ? 255 : gwi);
        coff[i] = ghc * 256 + gc;                      // always-in-bounds address
        mx[i] = (ghv && gwi == gc) ? 1.f : 0.f;        // zero-pad multiplier
    }

    // ---- H/D geometry: all 256 threads, 2 output rows each ----
    const int wcol = tid & 31;
    const int hb = (tid >> 5) * 2;   // 0..14

    f32x2 ringUV[2][7] = {};
    f32x2 ringSQ[2][7] = {};
    float lsum = 0.f;
    f32x2 cA[10], cB[10];   // depth-2 ping-pong slice buffers (raw x,y)

    // raw slice loader: 20 independent loads, NO dependent VALU at issue site
    auto LOADTO = [&](f32x2 (&buf)[10], int s) {
        const float* p1 = i1 + (size_t)s * HW;
        const float* p2 = i2 + (size_t)s * HW;
#pragma unroll
        for (int i = 0; i < 10; ++i) buf[i].x = p1[coff[i]];
#pragma unroll
        for (int i = 0; i < 10; ++i) buf[i].y = p2[coff[i]];
    };

    // prologue: slice r=0 -> cA, slice r=1 -> cB (skipped if out of range;
    // W-pass is also skipped for those r, so buffer contents don't matter)
    {
        const int s0 = o0 - 3;
        if (s0 >= 0 && wth) LOADTO(cA, s0);
        const int s1 = o0 - 2;
        if (s1 >= 0 && wth) LOADTO(cB, s1);
    }

#define PHASE(Q, CUR)                                                         \
    {                                                                         \
        const int r = 14 * t2 + (Q);                                          \
        if (r <= NSL) {                                                       \
            const int scur = o0 - 3 + r;                                      \
            const bool wv = (r < NSL) && (scur >= 0) && (scur < DD);          \
            /* 1) W-pass consumes CUR (loaded 2 iterations ago) */            \
            if (wv && wth) {                                                  \
                f32x2 aUV[4] = {};                                            \
                f32x2 aSQ[4] = {};                                            \
                _Pragma("unroll")                                             \
                for (int i = 0; i < 10; ++i) {                                \
                    f32x2 uv;                                                 \
                    uv.x = CUR[i].x + CUR[i].y;                               \
                    uv.y = CUR[i].x - CUR[i].y;                               \
                    uv = uv * s2(mx[i]);                                      \
                    const f32x2 sq = uv * uv;                                 \
                    _Pragma("unroll")                                         \
                    for (int o = 0; o < 4; ++o) {                             \
                        const int k = i - o;                                  \
                        if (k >= 0 && k < 7) {                                \
                            const float gk = gw.g[k];                         \
                            aUV[o] += s2(gk) * uv;                            \
                            aSQ[o] += s2(gk) * sq;                            \
                        }                                                     \
                    }                                                         \
                }                                                             \
                _Pragma("unroll")                                             \
                for (int o = 0; o < 4; ++o) {                                 \
                    pUV[(Q) & 1][wb + o][hh] = aUV[o];                        \
                    pSQ[(Q) & 1][wb + o][hh] = aSQ[o];                        \
                }                                                             \
            }                                                                 \
            /* 2) depth-2 prefetch: slice r+2 into CUR (consumed at r+2) */   \
            {                                                                 \
                const int sn2 = scur + 2;                                     \
                if ((r + 2 < NSL) && (sn2 >= 0) && (sn2 < DD) && wth)         \
                    LOADTO(CUR, sn2);                                         \
            }                                                                 \
            /* 3) H-pass + D-ring + SSIM for rp = r-1 (other plane buffer) */ \
            if (r >= 1) {                                                     \
                const int rp = r - 1;                                         \
                const int sp = o0 - 3 + rp;                                   \
                if (sp >= 0 && sp < DD) {                                     \
                    f32x2 vU[8], vS[8];                                       \
                    _Pragma("unroll")                                         \
                    for (int i = 0; i < 8; ++i) {                             \
                        vU[i] = pUV[((Q) + 1) & 1][wcol][hb + i];             \
                        vS[i] = pSQ[((Q) + 1) & 1][wcol][hb + i];             \
                    }                                                         \
                    _Pragma("unroll")                                         \
                    for (int o = 0; o < 2; ++o) {                             \
                        f32x2 aU = s2(0.f), aS = s2(0.f);                     \
                        _Pragma("unroll")                                     \
                        for (int k = 0; k < 7; ++k) {                         \
                            const float gk = gw.g[k];                         \
                            aU += s2(gk) * vU[o + k];                         \
                            aS += s2(gk) * vS[o + k];                         \
                        }                                                     \
                        ringUV[o][((Q) + 6) % 7] = aU;                        \
                        ringSQ[o][((Q) + 6) % 7] = aS;                        \
                    }                                                         \
                } else {                                                      \
                    _Pragma("unroll")                                         \
                    for (int o = 0; o < 2; ++o) {                             \
                        ringUV[o][((Q) + 6) % 7] = s2(0.f);                   \
                        ringSQ[o][((Q) + 6) % 7] = s2(0.f);                   \
                    }                                                         \
                }                                                             \
                if (r >= 7) {                                                 \
                    _Pragma("unroll")                                         \
                    for (int o = 0; o < 2; ++o) {                             \
                        f32x2 cU = s2(0.f), cS = s2(0.f);                     \
                        _Pragma("unroll")                                     \
                        for (int k = 0; k < 7; ++k) {                         \
                            const float gk = gw.g[k];                         \
                            const int pp = (((Q) + 6) % 7 + 1 + k) % 7;       \
                            cU += s2(gk) * ringUV[o][pp];                     \
                            cS += s2(gk) * ringSQ[o][pp];                     \
                        }                                                     \
                        /* A=conv(u), B=conv(v), P=conv(u^2), Q=conv(v^2) */  \
                        const f32x2 ab2 = cU * cU;                            \
                        const float sAB = ab2.x + ab2.y;                      \
                        const float dAB = ab2.x - ab2.y;                      \
                        const float sPQ = cS.x + cS.y;                        \
                        const float dPQ = cS.x - cS.y;                        \
                        const float num1 = 0.5f * dAB + SSIM_C1;              \
                        const float num2 = 0.5f * (dPQ - dAB) + SSIM_C2;      \
                        const float den1 = 0.5f * sAB + SSIM_C1;              \
                        const float den2 = 0.5f * (sPQ - sAB) + SSIM_C2;      \
                        lsum += (num1 * num2) *                               \
                                __builtin_amdgcn_rcpf(den1 * den2);           \
                    }                                                         \
                }                                                             \
            }                                                                 \
            __syncthreads();                                                  \
        }                                                                     \
    }

    for (int t2 = 0; t2 < 4; ++t2) {
        PHASE(0, cA)  PHASE(1, cB)  PHASE(2, cA)  PHASE(3, cB)
        PHASE(4, cA)  PHASE(5, cB)  PHASE(6, cA)  PHASE(7, cB)
        PHASE(8, cA)  PHASE(9, cB)  PHASE(10, cA) PHASE(11, cB)
        PHASE(12, cA) PHASE(13, cB)
    }
#undef PHASE

    // deterministic block reduction
    red[tid] = lsum;
    __syncthreads();
    for (int off = 128; off > 0; off >>= 1) {
        if (tid < off) red[tid] += red[tid + off];
        __syncthreads();
    }
    if (tid == 0)
        partials[(blockIdx.z * gridDim.y + blockIdx.y) * gridDim.x + blockIdx.x] = red[0];
}

__global__ __launch_bounds__(256) void k_final(
    const float* __restrict__ partials, int n, float scale, float* __restrict__ out)
{
    __shared__ float red[256];
    float s = 0.f;
    for (int i = threadIdx.x; i < n; i += 256) s += partials[i];
    red[threadIdx.x] = s;
    __syncthreads();
    for (int off = 128; off > 0; off >>= 1) {
        if (threadIdx.x < off) red[threadIdx.x] += red[threadIdx.x + off];
        __syncthreads();
    }
    if (threadIdx.x == 0) out[0] = red[0] * scale;
}

extern "C" void kernel_launch(void* const* d_in, const int* in_sizes, int n_in,
                              void* d_out, int out_size, void* d_ws, size_t ws_size,
                              hipStream_t stream)
{
    const float* img1 = (const float*)d_in[0];
    const float* img2 = (const float*)d_in[1];
    float* out = (float*)d_out;
    float* partials = (float*)d_ws;

    Gw gw;
    {
        double gs[7], sum = 0.0;
        for (int i = 0; i < 7; ++i) { double x = i - 3; gs[i] = exp(-x * x / 4.5); sum += gs[i]; }
        for (int i = 0; i < 7; ++i) gw.g[i] = (float)(gs[i] / sum);
    }

    dim3 grid(256 / TW, 256 / TH, NB * NCH);   // 8 x 16 x 8 = 1024 blocks
    k_fused<<<grid, dim3(256), 0, stream>>>(img1, img2, gw, partials);
    k_final<<<dim3(1), dim3(256), 0, stream>>>(
        partials, (256 / TW) * (256 / TH) * NB * NCH, (float)(1.0 / 20971520.0), out);
}